// Round 10
// baseline (137.698 us; speedup 1.0000x reference)
//
#include <hip/hip_runtime.h>
#include <cstdint>
#include <cstddef>

#define BATCH 1024
#define SEQL  128
#define DIM   768
#define HID   256
#define KIN1  1536
#define BN_EPS 1e-5f

typedef unsigned short u16;
typedef __attribute__((ext_vector_type(8))) short short8;
typedef __attribute__((ext_vector_type(4))) float f32x4;

__device__ __forceinline__ u16 f2bf(float f) {
  uint32_t u = __float_as_uint(f);
  return (u16)((u + 0x7fffu + ((u >> 16) & 1u)) >> 16);  // RNE, finite inputs
}
__device__ __forceinline__ float kred(float v) {  // reduce over kgrp lanes (lane bits 4,5)
  v += __shfl_xor(v, 16);
  v += __shfl_xor(v, 32);
  return v;
}

// ---------------- 1a. pool partials + weight-prep ----------------
// blocks 0..167: weight f32->bf16 (light, retire fast)
// blocks 168..4263: one (sample, tensor, row-chunk-of-64) each, 256 thr.
//   4096 chunk jobs >> ~2048 resident blocks -> HARDWARE REFILL does dynamic
//   load balancing (the thing 6 static-assignment variants lacked; all were
//   pinned at ~90us = mean + max-over-CUs of sum of random job lens).
//   Chunk partial sums (f32, 768 cols) written to part[pj]; combined by 1b.
#define PREP_BLK 168
#define NCHUNK_BLK 4096
#define NW1Q (DIM * KIN1 / 4)        // 294912 float4s
#define NW2Q (HID * DIM / 4)         // 49152

__global__ __launch_bounds__(256) void pool_partial_kernel(
    const float* __restrict__ uf, const float* __restrict__ hf,
    const int* __restrict__ ul, const int* __restrict__ hl,
    const float* __restrict__ w1, const float* __restrict__ w2,
    float* __restrict__ part, u16* __restrict__ w1b, u16* __restrict__ w2b) {
  const int id = blockIdx.x;
  const int tid = threadIdx.x;
  if (id < PREP_BLK) {
    const int base = id * 256 + tid;  // stride PREP_BLK*256 = 43008
#pragma unroll
    for (int s = 0; s < 8; ++s) {
      const int i = base + s * (PREP_BLK * 256);
      if (i < NW1Q) {
        f32x4 v = ((const f32x4*)w1)[i];
        ((ushort4*)w1b)[i] = make_ushort4(f2bf(v[0]), f2bf(v[1]), f2bf(v[2]), f2bf(v[3]));
      } else {
        const int i2 = i - NW1Q;
        if (i2 < NW2Q) {
          f32x4 v = ((const f32x4*)w2)[i2];
          ((ushort4*)w2b)[i2] = make_ushort4(f2bf(v[0]), f2bf(v[1]), f2bf(v[2]), f2bf(v[3]));
        }
      }
    }
    return;
  }
  const int pj = id - PREP_BLK;     // 0..4095
  const int c = pj & 1;             // chunk: rows [64c, min(len, 64c+64))
  const int j = pj >> 1;            // 0..2047
  const int b = j >> 1;
  const int which = j & 1;
  const int len = which ? hl[b] : ul[b];
  const int lo = c * 64;
  if (len <= lo) return;            // empty chunk: retires instantly, frees slot
  const int hi = (len < lo + 64) ? len : (lo + 64);

  __shared__ f32x4 sacc[4][192];
  const int wave = tid >> 6, lane = tid & 63;
  const f32x4* src = (const f32x4*)((which ? hf : uf) + (size_t)b * (SEQL * DIM));

  f32x4 a0 = (f32x4){0.f, 0.f, 0.f, 0.f}, a1 = a0, a2 = a0;
  f32x4 b0 = a0, b1 = a0, b2 = a0;
  int l = lo + wave;
  for (; l + 4 < hi; l += 8) {  // row pair (l, l+4): 6 x 1KB loads in flight
    f32x4 v0 = src[(size_t)l * 192 + lane];
    f32x4 v1 = src[(size_t)l * 192 + 64 + lane];
    f32x4 v2 = src[(size_t)l * 192 + 128 + lane];
    f32x4 u0 = src[(size_t)(l + 4) * 192 + lane];
    f32x4 u1 = src[(size_t)(l + 4) * 192 + 64 + lane];
    f32x4 u2 = src[(size_t)(l + 4) * 192 + 128 + lane];
    a0 += v0; a1 += v1; a2 += v2;
    b0 += u0; b1 += u1; b2 += u2;
  }
  if (l < hi) {
    a0 += src[(size_t)l * 192 + lane];
    a1 += src[(size_t)l * 192 + 64 + lane];
    a2 += src[(size_t)l * 192 + 128 + lane];
  }
  a0 += b0; a1 += b1; a2 += b2;

  sacc[wave][lane] = a0;
  sacc[wave][64 + lane] = a1;
  sacc[wave][128 + lane] = a2;
  __syncthreads();
  if (tid < 192) {
    f32x4 t = sacc[0][tid] + sacc[1][tid] + sacc[2][tid] + sacc[3][tid];
    ((f32x4*)part)[(size_t)pj * 192 + tid] = t;
  }
}

// ---------------- 1b. combine chunk partials -> xb (bf16) ----------------
// 2048 blocks x 192 thr; fixed chunk order 0,1 -> deterministic.
__global__ __launch_bounds__(192) void pool_combine_kernel(
    const int* __restrict__ ul, const int* __restrict__ hl,
    const float* __restrict__ part, u16* __restrict__ xb) {
  const int j = blockIdx.x;          // 0..2047
  const int b = j >> 1;
  const int which = j & 1;
  const int len = which ? hl[b] : ul[b];
  const int tid = threadIdx.x;       // 0..191
  const f32x4* base = (const f32x4*)part + (size_t)j * 384;  // 2 slots x 192
  f32x4 t = base[tid];
  if (len > 64) t += base[192 + tid];
  const float s = 1.f / (float)len;
  ushort4 o = make_ushort4(f2bf(t[0] * s), f2bf(t[1] * s), f2bf(t[2] * s), f2bf(t[3] * s));
  *(ushort4*)(xb + (size_t)b * KIN1 + which * DIM + tid * 4) = o;
}

// ---------------- 2. gemm1: y1 = xb @ w1b^T + b1; + column partials ----------------
// BM=64, BN=64, BK=64; 256 thr = 4 waves (2x2), wave tile 32x32 (2x2 frags)
// double-buffered LDS, one barrier/iter; XCD chunk swizzle (4bm x 6bn per XCD)
#define LDT 72  // padded row stride in u16

__global__ __launch_bounds__(256) void gemm1_kernel(
    const u16* __restrict__ A, const u16* __restrict__ W,
    const float* __restrict__ bias, float* __restrict__ y, float* __restrict__ p1) {
  __shared__ u16 lA[2][64 * LDT];
  __shared__ u16 lB[2][64 * LDT];
  __shared__ float red[2][64][2];
  const int K = KIN1, N = DIM;
  const int tid = threadIdx.x, lane = tid & 63, wv = tid >> 6;
  const int wr = wv >> 1, wc = wv & 1;
  const int r16 = lane & 15, kgrp = lane >> 4;
  const int d = blockIdx.x;
  const int g = d & 7, j = d >> 3;
  const int bm = (g >> 1) * 4 + (j & 3);   // 0..15
  const int bn = (g & 1) * 6 + (j >> 2);   // 0..11
  const int sr = tid >> 3, sc8 = (tid & 7) * 8;

  f32x4 acc[2][2];
#pragma unroll
  for (int mi = 0; mi < 2; ++mi)
#pragma unroll
    for (int ni = 0; ni < 2; ++ni) acc[mi][ni] = (f32x4){0.f, 0.f, 0.f, 0.f};

  const u16* Ab = A + (size_t)bm * 64 * K;
  const u16* Wb = W + (size_t)bn * 64 * K;

  uint4 ra0, ra1, rb0, rb1;
#define G1_LOAD(k0)                                              \
  ra0 = *(const uint4*)(Ab + (size_t)sr * K + (k0) + sc8);       \
  ra1 = *(const uint4*)(Ab + (size_t)(sr + 32) * K + (k0) + sc8);\
  rb0 = *(const uint4*)(Wb + (size_t)sr * K + (k0) + sc8);       \
  rb1 = *(const uint4*)(Wb + (size_t)(sr + 32) * K + (k0) + sc8);
#define G1_WRITE(buf)                                \
  *(uint4*)(lA[buf] + sr * LDT + sc8) = ra0;         \
  *(uint4*)(lA[buf] + (sr + 32) * LDT + sc8) = ra1;  \
  *(uint4*)(lB[buf] + sr * LDT + sc8) = rb0;         \
  *(uint4*)(lB[buf] + (sr + 32) * LDT + sc8) = rb1;

  G1_LOAD(0)
  G1_WRITE(0)
  __syncthreads();
  const int nk = K / 64;  // 24
  for (int ti = 0; ti < nk; ++ti) {
    const int cur = ti & 1;
    const bool more = (ti + 1 < nk);
    if (more) { G1_LOAD((ti + 1) * 64) }
#pragma unroll
    for (int kk = 0; kk < 2; ++kk) {
      const int koff = (kk * 4 + kgrp) * 8;
      short8 af0 = *(const short8*)(lA[cur] + (wr * 32 + r16) * LDT + koff);
      short8 af1 = *(const short8*)(lA[cur] + (wr * 32 + 16 + r16) * LDT + koff);
      short8 bf0 = *(const short8*)(lB[cur] + (wc * 32 + r16) * LDT + koff);
      short8 bf1 = *(const short8*)(lB[cur] + (wc * 32 + 16 + r16) * LDT + koff);
      acc[0][0] = __builtin_amdgcn_mfma_f32_16x16x32_bf16(af0, bf0, acc[0][0], 0, 0, 0);
      acc[0][1] = __builtin_amdgcn_mfma_f32_16x16x32_bf16(af0, bf1, acc[0][1], 0, 0, 0);
      acc[1][0] = __builtin_amdgcn_mfma_f32_16x16x32_bf16(af1, bf0, acc[1][0], 0, 0, 0);
      acc[1][1] = __builtin_amdgcn_mfma_f32_16x16x32_bf16(af1, bf1, acc[1][1], 0, 0, 0);
    }
    if (more) { G1_WRITE(cur ^ 1) }
    __syncthreads();
  }
#undef G1_LOAD
#undef G1_WRITE

#pragma unroll
  for (int ni = 0; ni < 2; ++ni) {
    const int col = bn * 64 + wc * 32 + ni * 16 + r16;
    const float bv = bias[col];
    float s = 0.f, s2 = 0.f;
#pragma unroll
    for (int mi = 0; mi < 2; ++mi)
#pragma unroll
      for (int rg = 0; rg < 4; ++rg) {
        const int row = bm * 64 + wr * 32 + mi * 16 + kgrp * 4 + rg;
        const float v = acc[mi][ni][rg] + bv;
        y[(size_t)row * N + col] = v;
        s += v; s2 += v * v;
      }
    s = kred(s); s2 = kred(s2);
    if (lane < 16) {
      red[wr][wc * 32 + ni * 16 + r16][0] = s;
      red[wr][wc * 32 + ni * 16 + r16][1] = s2;
    }
  }
  __syncthreads();
  if (tid < 128) {
    const int col = tid >> 1, wh = tid & 1;
    p1[((size_t)bm * DIM + bn * 64 + col) * 2 + wh] = red[0][col][wh] + red[1][col][wh];
  }
}

// ---------------- 3. gemm2: y2 = relu(bn1(y1)) @ w2b^T + b2; + column partials ----------------
// BM=32, BN=32 -> 256 blocks (full chip); 4 waves 2x2, wave tile 16x16; BN1 in A-staging
__global__ __launch_bounds__(256) void gemm2_kernel(
    const float* __restrict__ y1, const u16* __restrict__ W,
    const float* __restrict__ bias, const float* __restrict__ g, const float* __restrict__ be,
    const float* __restrict__ p1, float* __restrict__ y2, float* __restrict__ p2) {
  __shared__ u16 lA[2][32 * LDT];
  __shared__ u16 lB[2][32 * LDT];
  __shared__ float sS[DIM], sH[DIM];
  __shared__ float red[2][32][2];
  const int K = DIM, N = HID;
  const int tid = threadIdx.x, lane = tid & 63, wv = tid >> 6;
  const int wr = wv >> 1, wc = wv & 1;
  const int r16 = lane & 15, kgrp = lane >> 4;
  const int d = blockIdx.x;
  const int g8 = d & 7, j = d >> 3;     // XCD chunk: 4bm x 8bn per XCD
  const int bm = g8 * 4 + (j & 3);      // 0..31
  const int bn = j >> 2;                // 0..7
  const int sr = tid >> 3, sc8 = (tid & 7) * 8;

  for (int c = tid; c < DIM; c += 256) {
    float s = 0.f, s2 = 0.f;
#pragma unroll
    for (int i = 0; i < 16; ++i) {
      float2 pv = *(const float2*)(p1 + ((size_t)i * DIM + c) * 2);
      s += pv.x; s2 += pv.y;
    }
    const float m = s * (1.f / BATCH);
    const float var = s2 * (1.f / BATCH) - m * m;
    const float r = rsqrtf(var + BN_EPS);
    const float scl = r * g[c];
    sS[c] = scl;
    sH[c] = be[c] - m * scl;
  }
  __syncthreads();

  f32x4 acc = (f32x4){0.f, 0.f, 0.f, 0.f};
  const float* Ab = y1 + (size_t)bm * 32 * K;
  const u16* Wb = W + (size_t)bn * 32 * K;

  f32x4 va0, va1;
  uint4 rbq;
#define G2_LOAD(k0)                                          \
  va0 = *(const f32x4*)(Ab + (size_t)sr * K + (k0) + sc8);   \
  va1 = *(const f32x4*)(Ab + (size_t)sr * K + (k0) + sc8 + 4);\
  rbq = *(const uint4*)(Wb + (size_t)sr * K + (k0) + sc8);

  auto pack_write = [&](int buf, int k0) {
    union { ushort us[8]; uint4 q; } pk;
#pragma unroll
    for (int jj = 0; jj < 4; ++jj) {
      pk.us[jj]     = f2bf(fmaxf(0.f, va0[jj] * sS[k0 + sc8 + jj] + sH[k0 + sc8 + jj]));
      pk.us[4 + jj] = f2bf(fmaxf(0.f, va1[jj] * sS[k0 + sc8 + 4 + jj] + sH[k0 + sc8 + 4 + jj]));
    }
    *(uint4*)(lA[buf] + sr * LDT + sc8) = pk.q;
    *(uint4*)(lB[buf] + sr * LDT + sc8) = rbq;
  };

  G2_LOAD(0)
  pack_write(0, 0);
  __syncthreads();
  const int nk = K / 64;  // 12
  for (int ti = 0; ti < nk; ++ti) {
    const int cur = ti & 1;
    const bool more = (ti + 1 < nk);
    if (more) { G2_LOAD((ti + 1) * 64) }
#pragma unroll
    for (int kk = 0; kk < 2; ++kk) {
      const int koff = (kk * 4 + kgrp) * 8;
      short8 af0 = *(const short8*)(lA[cur] + (wr * 16 + r16) * LDT + koff);
      short8 bf0 = *(const short8*)(lB[cur] + (wc * 16 + r16) * LDT + koff);
      acc = __builtin_amdgcn_mfma_f32_16x16x32_bf16(af0, bf0, acc, 0, 0, 0);
    }
    if (more) pack_write(cur ^ 1, (ti + 1) * 64);
    __syncthreads();
  }
#undef G2_LOAD

  {
    const int col = bn * 32 + wc * 16 + r16;
    const float bv = bias[col];
    float s = 0.f, s2 = 0.f;
#pragma unroll
    for (int rg = 0; rg < 4; ++rg) {
      const int row = bm * 32 + wr * 16 + kgrp * 4 + rg;
      const float v = acc[rg] + bv;
      y2[(size_t)row * N + col] = v;
      s += v; s2 += v * v;
    }
    s = kred(s); s2 = kred(s2);
    if (lane < 16) {
      red[wr][wc * 16 + r16][0] = s;
      red[wr][wc * 16 + r16][1] = s2;
    }
  }
  __syncthreads();
  if (tid < 64) {
    const int col = tid >> 1, wh = tid & 1;
    p2[((size_t)bm * HID + bn * 32 + col) * 2 + wh] = red[0][col][wh] + red[1][col][wh];
  }
}

// ---------------- 4. fc3: out = sigmoid(relu(bn2(y2)) @ w3^T + b3) ----------------
__global__ __launch_bounds__(256) void fc3_kernel(
    const float* __restrict__ y2, const float* __restrict__ p2,
    const float* __restrict__ g, const float* __restrict__ be,
    const float* __restrict__ w3, const float* __restrict__ b3, float* __restrict__ out) {
  __shared__ float sS[HID], sH[HID];
  const int tid = threadIdx.x;
  {
    const int c = tid;
    float s = 0.f, s2 = 0.f;
#pragma unroll
    for (int i = 0; i < 32; ++i) {
      float2 pv = *(const float2*)(p2 + ((size_t)i * HID + c) * 2);
      s += pv.x; s2 += pv.y;
    }
    const float m = s * (1.f / BATCH);
    const float var = s2 * (1.f / BATCH) - m * m;
    const float r = rsqrtf(var + BN_EPS);
    const float scl = r * g[c];
    sS[c] = scl;
    sH[c] = be[c] - m * scl;
  }
  __syncthreads();
  const int row = blockIdx.x * 4 + (tid >> 6);
  const int lane = tid & 63;
  f32x4 xv = *(const f32x4*)(y2 + (size_t)row * HID + lane * 4);
  f32x4 sc = *(const f32x4*)&sS[lane * 4];
  f32x4 sh = *(const f32x4*)&sH[lane * 4];
  f32x4 wv = *(const f32x4*)(w3 + lane * 4);
  float dsum = 0.f;
#pragma unroll
  for (int jj = 0; jj < 4; ++jj) dsum += fmaxf(0.f, xv[jj] * sc[jj] + sh[jj]) * wv[jj];
#pragma unroll
  for (int off = 32; off > 0; off >>= 1) dsum += __shfl_xor(dsum, off);
  if (lane == 0) out[row] = 1.f / (1.f + expf(-(dsum + b3[0])));
}

// ---------------- launch ----------------
extern "C" void kernel_launch(void* const* d_in, const int* in_sizes, int n_in,
                              void* d_out, int out_size, void* d_ws, size_t ws_size,
                              hipStream_t stream) {
  const float* uf   = (const float*)d_in[0];
  const float* hf   = (const float*)d_in[1];
  const int*   ul   = (const int*)d_in[2];
  const int*   hl   = (const int*)d_in[3];
  const float* fc1w = (const float*)d_in[4];
  const float* fc1b = (const float*)d_in[5];
  const float* bn1g = (const float*)d_in[6];
  const float* bn1b = (const float*)d_in[7];
  const float* fc2w = (const float*)d_in[8];
  const float* fc2b = (const float*)d_in[9];
  const float* bn2g = (const float*)d_in[10];
  const float* bn2b = (const float*)d_in[11];
  const float* fc3w = (const float*)d_in[12];
  const float* fc3b = (const float*)d_in[13];
  float* out = (float*)d_out;

  char* ws = (char*)d_ws;
  u16*   xb   = (u16*)  (ws + 0);          // 1024*1536 bf16  (3145728 B)
  u16*   w1b  = (u16*)  (ws + 3145728);    // 768*1536 bf16   (2359296 B)
  u16*   w2b  = (u16*)  (ws + 5505024);    // 256*768 bf16    (393216 B)
  float* part = (float*)(ws + 5898240);    // 4096 slots * 3072 B = 12582912 B
                                           // (dead after combine; y1.. overlap it)
  float* y1   = (float*)(ws + 5898240);    // 1024*768 f32    (3145728 B)
  float* y2   = (float*)(ws + 9043968);    // 1024*256 f32    (1048576 B)
  float* p1   = (float*)(ws + 10092544);   // 16*768*2 f32    (98304 B)
  float* p2   = (float*)(ws + 10190848);   // 32*256*2 f32    (65536 B)

  pool_partial_kernel<<<PREP_BLK + NCHUNK_BLK, 256, 0, stream>>>(
      uf, hf, ul, hl, fc1w, fc2w, part, w1b, w2b);
  pool_combine_kernel<<<2048, 192, 0, stream>>>(ul, hl, part, xb);
  gemm1_kernel<<<192, 256, 0, stream>>>(xb, w1b, fc1b, y1, p1);
  gemm2_kernel<<<256, 256, 0, stream>>>(y1, w2b, fc2b, bn1g, bn1b, p1, y2, p2);
  fc3_kernel<<<256, 256, 0, stream>>>(y2, p2, bn2g, bn2b, fc3w, fc3b, out);
}

// Round 11
// 109.831 us; speedup vs baseline: 1.2537x; 1.2537x over previous
//
#include <hip/hip_runtime.h>
#include <cstdint>
#include <cstddef>

#define BATCH 1024
#define SEQL  128
#define DIM   768
#define HID   256
#define KIN1  1536
#define BN_EPS 1e-5f

typedef unsigned short u16;
typedef __attribute__((ext_vector_type(8))) short short8;
typedef __attribute__((ext_vector_type(4))) float f32x4;

__device__ __forceinline__ u16 f2bf(float f) {
  uint32_t u = __float_as_uint(f);
  return (u16)((u + 0x7fffu + ((u >> 16) & 1u)) >> 16);  // RNE, finite inputs
}
__device__ __forceinline__ f32x4 ntl(const f32x4* p) { return __builtin_nontemporal_load(p); }
__device__ __forceinline__ float kred(float v) {  // reduce over kgrp lanes (lane bits 4,5)
  v += __shfl_xor(v, 16);
  v += __shfl_xor(v, 32);
  return v;
}

// ---------------- 1. pool + weight-prep fused ----------------
// blocks 0..4095: ragged mean pool, one (sample, tensor, col-half) per block
//                 (col-split halves the max straggler block: <=192 KB each)
// blocks 4096..4543: f32->bf16 weight conversion (rides free under pool BW)
#define POOL_BLK 4096
#define PREP_BLK 448
#define NW1Q (DIM * KIN1 / 4)        // 294912 float4s
#define NWQ  (NW1Q + HID * DIM / 4)  // 344064

__global__ __launch_bounds__(96) void pool_prep_kernel(
    const float* __restrict__ uf, const float* __restrict__ hf,
    const int* __restrict__ ul, const int* __restrict__ hl,
    const float* __restrict__ w1, const float* __restrict__ w2,
    u16* __restrict__ xb, u16* __restrict__ w1b, u16* __restrict__ w2b) {
  const int id = blockIdx.x;
  const int t = threadIdx.x;  // 0..95
  if (id < POOL_BLK) {
    const int b = id >> 2;
    const int which = (id >> 1) & 1;
    const int half = id & 1;
    const f32x4* src = (const f32x4*)((which ? hf : uf) + (size_t)b * (SEQL * DIM)) + half * 96;
    const int len = which ? hl[b] : ul[b];
    f32x4 a0 = (f32x4){0.f, 0.f, 0.f, 0.f}, a1 = a0, a2 = a0, a3 = a0;
    int l = 0;
    for (; l + 8 <= len; l += 8) {
      f32x4 v0 = ntl(src + (size_t)(l + 0) * 192 + t);
      f32x4 v1 = ntl(src + (size_t)(l + 1) * 192 + t);
      f32x4 v2 = ntl(src + (size_t)(l + 2) * 192 + t);
      f32x4 v3 = ntl(src + (size_t)(l + 3) * 192 + t);
      f32x4 v4 = ntl(src + (size_t)(l + 4) * 192 + t);
      f32x4 v5 = ntl(src + (size_t)(l + 5) * 192 + t);
      f32x4 v6 = ntl(src + (size_t)(l + 6) * 192 + t);
      f32x4 v7 = ntl(src + (size_t)(l + 7) * 192 + t);
      a0 += v0; a1 += v1; a2 += v2; a3 += v3;
      a0 += v4; a1 += v5; a2 += v6; a3 += v7;
    }
    for (; l < len; ++l) a0 += ntl(src + (size_t)l * 192 + t);
    a0 += a1; a2 += a3; a0 += a2;
    const float s = 1.f / (float)len;
    ushort4 o = make_ushort4(f2bf(a0[0] * s), f2bf(a0[1] * s), f2bf(a0[2] * s), f2bf(a0[3] * s));
    *(ushort4*)(xb + (size_t)b * KIN1 + which * DIM + half * 384 + t * 4) = o;
  } else {
    const int j = id - POOL_BLK;
    const int base = j * 96 + t;  // stride PREP_BLK*96 = 43008
#pragma unroll
    for (int s = 0; s < 8; ++s) {
      const int i = base + s * (PREP_BLK * 96);
      if (i < NW1Q) {
        f32x4 v = ((const f32x4*)w1)[i];
        ((ushort4*)w1b)[i] = make_ushort4(f2bf(v[0]), f2bf(v[1]), f2bf(v[2]), f2bf(v[3]));
      } else {
        const int i2 = i - NW1Q;
        f32x4 v = ((const f32x4*)w2)[i2];
        ((ushort4*)w2b)[i2] = make_ushort4(f2bf(v[0]), f2bf(v[1]), f2bf(v[2]), f2bf(v[3]));
      }
    }
  }
}

// ---------------- 2. gemm1: y1 = xb @ w1b^T + b1; + column partials ----------------
// BM=64, BN=64, BK=64; 256 thr = 4 waves (2x2), wave tile 32x32 (2x2 frags)
// double-buffered LDS, one barrier/iter; XCD chunk swizzle (4bm x 6bn per XCD)
#define LDT 72  // padded row stride in u16

__global__ __launch_bounds__(256) void gemm1_kernel(
    const u16* __restrict__ A, const u16* __restrict__ W,
    const float* __restrict__ bias, float* __restrict__ y, float* __restrict__ p1) {
  __shared__ u16 lA[2][64 * LDT];
  __shared__ u16 lB[2][64 * LDT];
  __shared__ float red[2][64][2];
  const int K = KIN1, N = DIM;
  const int tid = threadIdx.x, lane = tid & 63, wv = tid >> 6;
  const int wr = wv >> 1, wc = wv & 1;
  const int r16 = lane & 15, kgrp = lane >> 4;
  const int d = blockIdx.x;
  const int g = d & 7, j = d >> 3;
  const int bm = (g >> 1) * 4 + (j & 3);   // 0..15
  const int bn = (g & 1) * 6 + (j >> 2);   // 0..11
  const int sr = tid >> 3, sc8 = (tid & 7) * 8;

  f32x4 acc[2][2];
#pragma unroll
  for (int mi = 0; mi < 2; ++mi)
#pragma unroll
    for (int ni = 0; ni < 2; ++ni) acc[mi][ni] = (f32x4){0.f, 0.f, 0.f, 0.f};

  const u16* Ab = A + (size_t)bm * 64 * K;
  const u16* Wb = W + (size_t)bn * 64 * K;

  uint4 ra0, ra1, rb0, rb1;
#define G1_LOAD(k0)                                              \
  ra0 = *(const uint4*)(Ab + (size_t)sr * K + (k0) + sc8);       \
  ra1 = *(const uint4*)(Ab + (size_t)(sr + 32) * K + (k0) + sc8);\
  rb0 = *(const uint4*)(Wb + (size_t)sr * K + (k0) + sc8);       \
  rb1 = *(const uint4*)(Wb + (size_t)(sr + 32) * K + (k0) + sc8);
#define G1_WRITE(buf)                                \
  *(uint4*)(lA[buf] + sr * LDT + sc8) = ra0;         \
  *(uint4*)(lA[buf] + (sr + 32) * LDT + sc8) = ra1;  \
  *(uint4*)(lB[buf] + sr * LDT + sc8) = rb0;         \
  *(uint4*)(lB[buf] + (sr + 32) * LDT + sc8) = rb1;

  G1_LOAD(0)
  G1_WRITE(0)
  __syncthreads();
  const int nk = K / 64;  // 24
  for (int ti = 0; ti < nk; ++ti) {
    const int cur = ti & 1;
    const bool more = (ti + 1 < nk);
    if (more) { G1_LOAD((ti + 1) * 64) }
#pragma unroll
    for (int kk = 0; kk < 2; ++kk) {
      const int koff = (kk * 4 + kgrp) * 8;
      short8 af0 = *(const short8*)(lA[cur] + (wr * 32 + r16) * LDT + koff);
      short8 af1 = *(const short8*)(lA[cur] + (wr * 32 + 16 + r16) * LDT + koff);
      short8 bf0 = *(const short8*)(lB[cur] + (wc * 32 + r16) * LDT + koff);
      short8 bf1 = *(const short8*)(lB[cur] + (wc * 32 + 16 + r16) * LDT + koff);
      acc[0][0] = __builtin_amdgcn_mfma_f32_16x16x32_bf16(af0, bf0, acc[0][0], 0, 0, 0);
      acc[0][1] = __builtin_amdgcn_mfma_f32_16x16x32_bf16(af0, bf1, acc[0][1], 0, 0, 0);
      acc[1][0] = __builtin_amdgcn_mfma_f32_16x16x32_bf16(af1, bf0, acc[1][0], 0, 0, 0);
      acc[1][1] = __builtin_amdgcn_mfma_f32_16x16x32_bf16(af1, bf1, acc[1][1], 0, 0, 0);
    }
    if (more) { G1_WRITE(cur ^ 1) }
    __syncthreads();
  }

#pragma unroll
  for (int ni = 0; ni < 2; ++ni) {
    const int col = bn * 64 + wc * 32 + ni * 16 + r16;
    const float bv = bias[col];
    float s = 0.f, s2 = 0.f;
#pragma unroll
    for (int mi = 0; mi < 2; ++mi)
#pragma unroll
      for (int rg = 0; rg < 4; ++rg) {
        const int row = bm * 64 + wr * 32 + mi * 16 + kgrp * 4 + rg;
        const float v = acc[mi][ni][rg] + bv;
        y[(size_t)row * N + col] = v;
        s += v; s2 += v * v;
      }
    s = kred(s); s2 = kred(s2);
    if (lane < 16) {
      red[wr][wc * 32 + ni * 16 + r16][0] = s;
      red[wr][wc * 32 + ni * 16 + r16][1] = s2;
    }
  }
  __syncthreads();
  if (tid < 128) {
    const int col = tid >> 1, wh = tid & 1;
    p1[((size_t)bm * DIM + bn * 64 + col) * 2 + wh] = red[0][col][wh] + red[1][col][wh];
  }
}

// ---------------- 3. gemm2: y2 = relu(bn1(y1)) @ w2b^T + b2; + column partials ----------------
// BM=32, BN=32 -> 256 blocks (full chip); 4 waves 2x2, wave tile 16x16; BN1 in A-staging
__global__ __launch_bounds__(256) void gemm2_kernel(
    const float* __restrict__ y1, const u16* __restrict__ W,
    const float* __restrict__ bias, const float* __restrict__ g, const float* __restrict__ be,
    const float* __restrict__ p1, float* __restrict__ y2, float* __restrict__ p2) {
  __shared__ u16 lA[2][32 * LDT];
  __shared__ u16 lB[2][32 * LDT];
  __shared__ float sS[DIM], sH[DIM];
  __shared__ float red[2][32][2];
  const int K = DIM, N = HID;
  const int tid = threadIdx.x, lane = tid & 63, wv = tid >> 6;
  const int wr = wv >> 1, wc = wv & 1;
  const int r16 = lane & 15, kgrp = lane >> 4;
  const int d = blockIdx.x;
  const int g8 = d & 7, j = d >> 3;     // XCD chunk: 4bm x 8bn per XCD
  const int bm = g8 * 4 + (j & 3);      // 0..31
  const int bn = j >> 2;                // 0..7
  const int sr = tid >> 3, sc8 = (tid & 7) * 8;

  for (int c = tid; c < DIM; c += 256) {
    float s = 0.f, s2 = 0.f;
#pragma unroll
    for (int i = 0; i < 16; ++i) {
      float2 pv = *(const float2*)(p1 + ((size_t)i * DIM + c) * 2);
      s += pv.x; s2 += pv.y;
    }
    const float m = s * (1.f / BATCH);
    const float var = s2 * (1.f / BATCH) - m * m;
    const float r = rsqrtf(var + BN_EPS);
    const float scl = r * g[c];
    sS[c] = scl;
    sH[c] = be[c] - m * scl;
  }
  __syncthreads();

  f32x4 acc = (f32x4){0.f, 0.f, 0.f, 0.f};
  const float* Ab = y1 + (size_t)bm * 32 * K;
  const u16* Wb = W + (size_t)bn * 32 * K;

  f32x4 va0, va1;
  uint4 rbq;
#define G2_LOAD(k0)                                          \
  va0 = *(const f32x4*)(Ab + (size_t)sr * K + (k0) + sc8);   \
  va1 = *(const f32x4*)(Ab + (size_t)sr * K + (k0) + sc8 + 4);\
  rbq = *(const uint4*)(Wb + (size_t)sr * K + (k0) + sc8);

  auto pack_write = [&](int buf, int k0) {
    union { ushort us[8]; uint4 q; } pk;
#pragma unroll
    for (int jj = 0; jj < 4; ++jj) {
      pk.us[jj]     = f2bf(fmaxf(0.f, va0[jj] * sS[k0 + sc8 + jj] + sH[k0 + sc8 + jj]));
      pk.us[4 + jj] = f2bf(fmaxf(0.f, va1[jj] * sS[k0 + sc8 + 4 + jj] + sH[k0 + sc8 + 4 + jj]));
    }
    *(uint4*)(lA[buf] + sr * LDT + sc8) = pk.q;
    *(uint4*)(lB[buf] + sr * LDT + sc8) = rbq;
  };

  G2_LOAD(0)
  pack_write(0, 0);
  __syncthreads();
  const int nk = K / 64;  // 12
  for (int ti = 0; ti < nk; ++ti) {
    const int cur = ti & 1;
    const bool more = (ti + 1 < nk);
    if (more) { G2_LOAD((ti + 1) * 64) }
#pragma unroll
    for (int kk = 0; kk < 2; ++kk) {
      const int koff = (kk * 4 + kgrp) * 8;
      short8 af0 = *(const short8*)(lA[cur] + (wr * 16 + r16) * LDT + koff);
      short8 bf0 = *(const short8*)(lB[cur] + (wc * 16 + r16) * LDT + koff);
      acc = __builtin_amdgcn_mfma_f32_16x16x32_bf16(af0, bf0, acc, 0, 0, 0);
    }
    if (more) pack_write(cur ^ 1, (ti + 1) * 64);
    __syncthreads();
  }

  {
    const int col = bn * 32 + wc * 16 + r16;
    const float bv = bias[col];
    float s = 0.f, s2 = 0.f;
#pragma unroll
    for (int rg = 0; rg < 4; ++rg) {
      const int row = bm * 32 + wr * 16 + kgrp * 4 + rg;
      const float v = acc[rg] + bv;
      y2[(size_t)row * N + col] = v;
      s += v; s2 += v * v;
    }
    s = kred(s); s2 = kred(s2);
    if (lane < 16) {
      red[wr][wc * 16 + r16][0] = s;
      red[wr][wc * 16 + r16][1] = s2;
    }
  }
  __syncthreads();
  if (tid < 64) {
    const int col = tid >> 1, wh = tid & 1;
    p2[((size_t)bm * HID + bn * 32 + col) * 2 + wh] = red[0][col][wh] + red[1][col][wh];
  }
}

// ---------------- 4. fc3: out = sigmoid(relu(bn2(y2)) @ w3^T + b3) ----------------
__global__ __launch_bounds__(256) void fc3_kernel(
    const float* __restrict__ y2, const float* __restrict__ p2,
    const float* __restrict__ g, const float* __restrict__ be,
    const float* __restrict__ w3, const float* __restrict__ b3, float* __restrict__ out) {
  __shared__ float sS[HID], sH[HID];
  const int tid = threadIdx.x;
  {
    const int c = tid;
    float s = 0.f, s2 = 0.f;
#pragma unroll
    for (int i = 0; i < 32; ++i) {
      float2 pv = *(const float2*)(p2 + ((size_t)i * HID + c) * 2);
      s += pv.x; s2 += pv.y;
    }
    const float m = s * (1.f / BATCH);
    const float var = s2 * (1.f / BATCH) - m * m;
    const float r = rsqrtf(var + BN_EPS);
    const float scl = r * g[c];
    sS[c] = scl;
    sH[c] = be[c] - m * scl;
  }
  __syncthreads();
  const int row = blockIdx.x * 4 + (tid >> 6);
  const int lane = tid & 63;
  f32x4 xv = *(const f32x4*)(y2 + (size_t)row * HID + lane * 4);
  f32x4 sc = *(const f32x4*)&sS[lane * 4];
  f32x4 sh = *(const f32x4*)&sH[lane * 4];
  f32x4 wv = *(const f32x4*)(w3 + lane * 4);
  float dsum = 0.f;
#pragma unroll
  for (int jj = 0; jj < 4; ++jj) dsum += fmaxf(0.f, xv[jj] * sc[jj] + sh[jj]) * wv[jj];
#pragma unroll
  for (int off = 32; off > 0; off >>= 1) dsum += __shfl_xor(dsum, off);
  if (lane == 0) out[row] = 1.f / (1.f + expf(-(dsum + b3[0])));
}

// ---------------- launch ----------------
extern "C" void kernel_launch(void* const* d_in, const int* in_sizes, int n_in,
                              void* d_out, int out_size, void* d_ws, size_t ws_size,
                              hipStream_t stream) {
  const float* uf   = (const float*)d_in[0];
  const float* hf   = (const float*)d_in[1];
  const int*   ul   = (const int*)d_in[2];
  const int*   hl   = (const int*)d_in[3];
  const float* fc1w = (const float*)d_in[4];
  const float* fc1b = (const float*)d_in[5];
  const float* bn1g = (const float*)d_in[6];
  const float* bn1b = (const float*)d_in[7];
  const float* fc2w = (const float*)d_in[8];
  const float* fc2b = (const float*)d_in[9];
  const float* bn2g = (const float*)d_in[10];
  const float* bn2b = (const float*)d_in[11];
  const float* fc3w = (const float*)d_in[12];
  const float* fc3b = (const float*)d_in[13];
  float* out = (float*)d_out;

  char* ws = (char*)d_ws;
  u16*   xb  = (u16*)  (ws + 0);          // 1024*1536 bf16  (3145728 B)
  u16*   w1b = (u16*)  (ws + 3145728);    // 768*1536 bf16   (2359296 B)
  u16*   w2b = (u16*)  (ws + 5505024);    // 256*768 bf16    (393216 B)
  float* y1  = (float*)(ws + 5898240);    // 1024*768 f32    (3145728 B)
  float* y2  = (float*)(ws + 9043968);    // 1024*256 f32    (1048576 B)
  float* p1  = (float*)(ws + 10092544);   // 16*768*2 f32    (98304 B)
  float* p2  = (float*)(ws + 10190848);   // 32*256*2 f32    (65536 B)

  pool_prep_kernel<<<POOL_BLK + PREP_BLK, 96, 0, stream>>>(uf, hf, ul, hl, fc1w, fc2w, xb, w1b, w2b);
  gemm1_kernel<<<192, 256, 0, stream>>>(xb, w1b, fc1b, y1, p1);
  gemm2_kernel<<<256, 256, 0, stream>>>(y1, w2b, fc2b, bn1g, bn1b, p1, y2, p2);
  fc3_kernel<<<256, 256, 0, stream>>>(y2, p2, bn2g, bn2b, fc3w, fc3b, out);
}

// Round 12
// 107.492 us; speedup vs baseline: 1.2810x; 1.0218x over previous
//
#include <hip/hip_runtime.h>
#include <cstdint>
#include <cstddef>

#define BATCH 1024
#define SEQL  128
#define DIM   768
#define HID   256
#define KIN1  1536
#define BN_EPS 1e-5f

typedef unsigned short u16;
typedef __attribute__((ext_vector_type(8))) short short8;
typedef __attribute__((ext_vector_type(4))) float f32x4;

__device__ __forceinline__ u16 f2bf(float f) {
  uint32_t u = __float_as_uint(f);
  return (u16)((u + 0x7fffu + ((u >> 16) & 1u)) >> 16);  // RNE, finite inputs
}
__device__ __forceinline__ f32x4 ntl(const f32x4* p) { return __builtin_nontemporal_load(p); }
__device__ __forceinline__ float kred(float v) {  // reduce over kgrp lanes (lane bits 4,5)
  v += __shfl_xor(v, 16);
  v += __shfl_xor(v, 32);
  return v;
}

// ---------------- 1. pool + weight-prep fused (R5/R11 verbatim: 109.8us x2) ----------------
// blocks 0..4095: ragged mean pool, one (sample, tensor, col-half) per block
// blocks 4096..4543: f32->bf16 weight conversion (rides free under pool BW)
#define POOL_BLK 4096
#define PREP_BLK 448
#define NW1Q (DIM * KIN1 / 4)        // 294912 float4s
#define NWQ  (NW1Q + HID * DIM / 4)  // 344064

__global__ __launch_bounds__(96) void pool_prep_kernel(
    const float* __restrict__ uf, const float* __restrict__ hf,
    const int* __restrict__ ul, const int* __restrict__ hl,
    const float* __restrict__ w1, const float* __restrict__ w2,
    u16* __restrict__ xb, u16* __restrict__ w1b, u16* __restrict__ w2b) {
  const int id = blockIdx.x;
  const int t = threadIdx.x;  // 0..95
  if (id < POOL_BLK) {
    const int b = id >> 2;
    const int which = (id >> 1) & 1;
    const int half = id & 1;
    const f32x4* src = (const f32x4*)((which ? hf : uf) + (size_t)b * (SEQL * DIM)) + half * 96;
    const int len = which ? hl[b] : ul[b];
    f32x4 a0 = (f32x4){0.f, 0.f, 0.f, 0.f}, a1 = a0, a2 = a0, a3 = a0;
    int l = 0;
    for (; l + 8 <= len; l += 8) {
      f32x4 v0 = ntl(src + (size_t)(l + 0) * 192 + t);
      f32x4 v1 = ntl(src + (size_t)(l + 1) * 192 + t);
      f32x4 v2 = ntl(src + (size_t)(l + 2) * 192 + t);
      f32x4 v3 = ntl(src + (size_t)(l + 3) * 192 + t);
      f32x4 v4 = ntl(src + (size_t)(l + 4) * 192 + t);
      f32x4 v5 = ntl(src + (size_t)(l + 5) * 192 + t);
      f32x4 v6 = ntl(src + (size_t)(l + 6) * 192 + t);
      f32x4 v7 = ntl(src + (size_t)(l + 7) * 192 + t);
      a0 += v0; a1 += v1; a2 += v2; a3 += v3;
      a0 += v4; a1 += v5; a2 += v6; a3 += v7;
    }
    for (; l < len; ++l) a0 += ntl(src + (size_t)l * 192 + t);
    a0 += a1; a2 += a3; a0 += a2;
    const float s = 1.f / (float)len;
    ushort4 o = make_ushort4(f2bf(a0[0] * s), f2bf(a0[1] * s), f2bf(a0[2] * s), f2bf(a0[3] * s));
    *(ushort4*)(xb + (size_t)b * KIN1 + which * DIM + half * 384 + t * 4) = o;
  } else {
    const int j = id - POOL_BLK;
    const int base = j * 96 + t;  // stride PREP_BLK*96 = 43008
#pragma unroll
    for (int s = 0; s < 8; ++s) {
      const int i = base + s * (PREP_BLK * 96);
      if (i < NW1Q) {
        f32x4 v = ((const f32x4*)w1)[i];
        ((ushort4*)w1b)[i] = make_ushort4(f2bf(v[0]), f2bf(v[1]), f2bf(v[2]), f2bf(v[3]));
      } else {
        const int i2 = i - NW1Q;
        f32x4 v = ((const f32x4*)w2)[i2];
        ((ushort4*)w2b)[i2] = make_ushort4(f2bf(v[0]), f2bf(v[1]), f2bf(v[2]), f2bf(v[3]));
      }
    }
  }
}

// ---------------- 2. gemm1: y1 = xb @ w1b^T + b1; + column partials ----------------
// BM=64, BN=32, BK=64 -> 384 blocks (1.5/CU, was 192 = 0.75/CU); 4 waves (2x2),
// wave tile 32x16 (2x1 frags); double-buffered LDS, one barrier/iter;
// XCD chunk swizzle: 4bm x 12bn per XCD.
#define LDT 72  // padded row stride in u16

__global__ __launch_bounds__(256) void gemm1_kernel(
    const u16* __restrict__ A, const u16* __restrict__ W,
    const float* __restrict__ bias, float* __restrict__ y, float* __restrict__ p1) {
  __shared__ u16 lA[2][64 * LDT];
  __shared__ u16 lB[2][32 * LDT];
  __shared__ float red[2][32][2];
  const int K = KIN1, N = DIM;
  const int tid = threadIdx.x, lane = tid & 63, wv = tid >> 6;
  const int wr = wv >> 1, wc = wv & 1;
  const int r16 = lane & 15, kgrp = lane >> 4;
  const int d = blockIdx.x;
  const int g = d & 7, j = d >> 3;         // j = 0..47 within XCD
  const int bm = (g >> 1) * 4 + (j & 3);   // 0..15
  const int bn = (g & 1) * 12 + (j >> 2);  // 0..23
  const int sr = tid >> 3, sc8 = (tid & 7) * 8;

  f32x4 acc[2];
  acc[0] = (f32x4){0.f, 0.f, 0.f, 0.f};
  acc[1] = acc[0];

  const u16* Ab = A + (size_t)bm * 64 * K;
  const u16* Wb = W + (size_t)bn * 32 * K;

  uint4 ra0, ra1, rb0;
#define G1_LOAD(k0)                                              \
  ra0 = *(const uint4*)(Ab + (size_t)sr * K + (k0) + sc8);       \
  ra1 = *(const uint4*)(Ab + (size_t)(sr + 32) * K + (k0) + sc8);\
  rb0 = *(const uint4*)(Wb + (size_t)sr * K + (k0) + sc8);
#define G1_WRITE(buf)                                \
  *(uint4*)(lA[buf] + sr * LDT + sc8) = ra0;         \
  *(uint4*)(lA[buf] + (sr + 32) * LDT + sc8) = ra1;  \
  *(uint4*)(lB[buf] + sr * LDT + sc8) = rb0;

  G1_LOAD(0)
  G1_WRITE(0)
  __syncthreads();
  const int nk = K / 64;  // 24
  for (int ti = 0; ti < nk; ++ti) {
    const int cur = ti & 1;
    const bool more = (ti + 1 < nk);
    if (more) { G1_LOAD((ti + 1) * 64) }
#pragma unroll
    for (int kk = 0; kk < 2; ++kk) {
      const int koff = (kk * 4 + kgrp) * 8;
      short8 af0 = *(const short8*)(lA[cur] + (wr * 32 + r16) * LDT + koff);
      short8 af1 = *(const short8*)(lA[cur] + (wr * 32 + 16 + r16) * LDT + koff);
      short8 bf0 = *(const short8*)(lB[cur] + (wc * 16 + r16) * LDT + koff);
      acc[0] = __builtin_amdgcn_mfma_f32_16x16x32_bf16(af0, bf0, acc[0], 0, 0, 0);
      acc[1] = __builtin_amdgcn_mfma_f32_16x16x32_bf16(af1, bf0, acc[1], 0, 0, 0);
    }
    if (more) { G1_WRITE(cur ^ 1) }
    __syncthreads();
  }
#undef G1_LOAD
#undef G1_WRITE

  {
    const int col = bn * 32 + wc * 16 + r16;
    const float bv = bias[col];
    float s = 0.f, s2 = 0.f;
#pragma unroll
    for (int mi = 0; mi < 2; ++mi)
#pragma unroll
      for (int rg = 0; rg < 4; ++rg) {
        const int row = bm * 64 + wr * 32 + mi * 16 + kgrp * 4 + rg;
        const float v = acc[mi][rg] + bv;
        y[(size_t)row * N + col] = v;
        s += v; s2 += v * v;
      }
    s = kred(s); s2 = kred(s2);
    if (lane < 16) {
      red[wr][wc * 16 + r16][0] = s;
      red[wr][wc * 16 + r16][1] = s2;
    }
  }
  __syncthreads();
  if (tid < 64) {
    const int col = tid >> 1, wh = tid & 1;
    p1[((size_t)bm * DIM + bn * 32 + col) * 2 + wh] = red[0][col][wh] + red[1][col][wh];
  }
}

// ---------------- 3. gemm2: y2 = relu(bn1(y1)) @ w2b^T + b2; + column partials ----------------
// BM=32, BN=32 -> 256 blocks (full chip); 4 waves 2x2, wave tile 16x16; BN1 in A-staging
__global__ __launch_bounds__(256) void gemm2_kernel(
    const float* __restrict__ y1, const u16* __restrict__ W,
    const float* __restrict__ bias, const float* __restrict__ g, const float* __restrict__ be,
    const float* __restrict__ p1, float* __restrict__ y2, float* __restrict__ p2) {
  __shared__ u16 lA[2][32 * LDT];
  __shared__ u16 lB[2][32 * LDT];
  __shared__ float sS[DIM], sH[DIM];
  __shared__ float red[2][32][2];
  const int K = DIM, N = HID;
  const int tid = threadIdx.x, lane = tid & 63, wv = tid >> 6;
  const int wr = wv >> 1, wc = wv & 1;
  const int r16 = lane & 15, kgrp = lane >> 4;
  const int d = blockIdx.x;
  const int g8 = d & 7, j = d >> 3;     // XCD chunk: 4bm x 8bn per XCD
  const int bm = g8 * 4 + (j & 3);      // 0..31
  const int bn = j >> 2;                // 0..7
  const int sr = tid >> 3, sc8 = (tid & 7) * 8;

  for (int c = tid; c < DIM; c += 256) {
    float s = 0.f, s2 = 0.f;
#pragma unroll
    for (int i = 0; i < 16; ++i) {
      float2 pv = *(const float2*)(p1 + ((size_t)i * DIM + c) * 2);
      s += pv.x; s2 += pv.y;
    }
    const float m = s * (1.f / BATCH);
    const float var = s2 * (1.f / BATCH) - m * m;
    const float r = rsqrtf(var + BN_EPS);
    const float scl = r * g[c];
    sS[c] = scl;
    sH[c] = be[c] - m * scl;
  }
  __syncthreads();

  f32x4 acc = (f32x4){0.f, 0.f, 0.f, 0.f};
  const float* Ab = y1 + (size_t)bm * 32 * K;
  const u16* Wb = W + (size_t)bn * 32 * K;

  f32x4 va0, va1;
  uint4 rbq;
#define G2_LOAD(k0)                                          \
  va0 = *(const f32x4*)(Ab + (size_t)sr * K + (k0) + sc8);   \
  va1 = *(const f32x4*)(Ab + (size_t)sr * K + (k0) + sc8 + 4);\
  rbq = *(const uint4*)(Wb + (size_t)sr * K + (k0) + sc8);

  auto pack_write = [&](int buf, int k0) {
    union { ushort us[8]; uint4 q; } pk;
#pragma unroll
    for (int jj = 0; jj < 4; ++jj) {
      pk.us[jj]     = f2bf(fmaxf(0.f, va0[jj] * sS[k0 + sc8 + jj] + sH[k0 + sc8 + jj]));
      pk.us[4 + jj] = f2bf(fmaxf(0.f, va1[jj] * sS[k0 + sc8 + 4 + jj] + sH[k0 + sc8 + 4 + jj]));
    }
    *(uint4*)(lA[buf] + sr * LDT + sc8) = pk.q;
    *(uint4*)(lB[buf] + sr * LDT + sc8) = rbq;
  };

  G2_LOAD(0)
  pack_write(0, 0);
  __syncthreads();
  const int nk = K / 64;  // 12
  for (int ti = 0; ti < nk; ++ti) {
    const int cur = ti & 1;
    const bool more = (ti + 1 < nk);
    if (more) { G2_LOAD((ti + 1) * 64) }
#pragma unroll
    for (int kk = 0; kk < 2; ++kk) {
      const int koff = (kk * 4 + kgrp) * 8;
      short8 af0 = *(const short8*)(lA[cur] + (wr * 16 + r16) * LDT + koff);
      short8 bf0 = *(const short8*)(lB[cur] + (wc * 16 + r16) * LDT + koff);
      acc = __builtin_amdgcn_mfma_f32_16x16x32_bf16(af0, bf0, acc, 0, 0, 0);
    }
    if (more) pack_write(cur ^ 1, (ti + 1) * 64);
    __syncthreads();
  }
#undef G2_LOAD

  {
    const int col = bn * 32 + wc * 16 + r16;
    const float bv = bias[col];
    float s = 0.f, s2 = 0.f;
#pragma unroll
    for (int rg = 0; rg < 4; ++rg) {
      const int row = bm * 32 + wr * 16 + kgrp * 4 + rg;
      const float v = acc[rg] + bv;
      y2[(size_t)row * N + col] = v;
      s += v; s2 += v * v;
    }
    s = kred(s); s2 = kred(s2);
    if (lane < 16) {
      red[wr][wc * 16 + r16][0] = s;
      red[wr][wc * 16 + r16][1] = s2;
    }
  }
  __syncthreads();
  if (tid < 64) {
    const int col = tid >> 1, wh = tid & 1;
    p2[((size_t)bm * HID + bn * 32 + col) * 2 + wh] = red[0][col][wh] + red[1][col][wh];
  }
}

// ---------------- 4. fc3: out = sigmoid(relu(bn2(y2)) @ w3^T + b3) ----------------
__global__ __launch_bounds__(256) void fc3_kernel(
    const float* __restrict__ y2, const float* __restrict__ p2,
    const float* __restrict__ g, const float* __restrict__ be,
    const float* __restrict__ w3, const float* __restrict__ b3, float* __restrict__ out) {
  __shared__ float sS[HID], sH[HID];
  const int tid = threadIdx.x;
  {
    const int c = tid;
    float s = 0.f, s2 = 0.f;
#pragma unroll
    for (int i = 0; i < 32; ++i) {
      float2 pv = *(const float2*)(p2 + ((size_t)i * HID + c) * 2);
      s += pv.x; s2 += pv.y;
    }
    const float m = s * (1.f / BATCH);
    const float var = s2 * (1.f / BATCH) - m * m;
    const float r = rsqrtf(var + BN_EPS);
    const float scl = r * g[c];
    sS[c] = scl;
    sH[c] = be[c] - m * scl;
  }
  __syncthreads();
  const int row = blockIdx.x * 4 + (tid >> 6);
  const int lane = tid & 63;
  f32x4 xv = *(const f32x4*)(y2 + (size_t)row * HID + lane * 4);
  f32x4 sc = *(const f32x4*)&sS[lane * 4];
  f32x4 sh = *(const f32x4*)&sH[lane * 4];
  f32x4 wv = *(const f32x4*)(w3 + lane * 4);
  float dsum = 0.f;
#pragma unroll
  for (int jj = 0; jj < 4; ++jj) dsum += fmaxf(0.f, xv[jj] * sc[jj] + sh[jj]) * wv[jj];
#pragma unroll
  for (int off = 32; off > 0; off >>= 1) dsum += __shfl_xor(dsum, off);
  if (lane == 0) out[row] = 1.f / (1.f + expf(-(dsum + b3[0])));
}

// ---------------- launch ----------------
extern "C" void kernel_launch(void* const* d_in, const int* in_sizes, int n_in,
                              void* d_out, int out_size, void* d_ws, size_t ws_size,
                              hipStream_t stream) {
  const float* uf   = (const float*)d_in[0];
  const float* hf   = (const float*)d_in[1];
  const int*   ul   = (const int*)d_in[2];
  const int*   hl   = (const int*)d_in[3];
  const float* fc1w = (const float*)d_in[4];
  const float* fc1b = (const float*)d_in[5];
  const float* bn1g = (const float*)d_in[6];
  const float* bn1b = (const float*)d_in[7];
  const float* fc2w = (const float*)d_in[8];
  const float* fc2b = (const float*)d_in[9];
  const float* bn2g = (const float*)d_in[10];
  const float* bn2b = (const float*)d_in[11];
  const float* fc3w = (const float*)d_in[12];
  const float* fc3b = (const float*)d_in[13];
  float* out = (float*)d_out;

  char* ws = (char*)d_ws;
  u16*   xb  = (u16*)  (ws + 0);          // 1024*1536 bf16  (3145728 B)
  u16*   w1b = (u16*)  (ws + 3145728);    // 768*1536 bf16   (2359296 B)
  u16*   w2b = (u16*)  (ws + 5505024);    // 256*768 bf16    (393216 B)
  float* y1  = (float*)(ws + 5898240);    // 1024*768 f32    (3145728 B)
  float* y2  = (float*)(ws + 9043968);    // 1024*256 f32    (1048576 B)
  float* p1  = (float*)(ws + 10092544);   // 16*768*2 f32    (98304 B)
  float* p2  = (float*)(ws + 10190848);   // 32*256*2 f32    (65536 B)

  pool_prep_kernel<<<POOL_BLK + PREP_BLK, 96, 0, stream>>>(uf, hf, ul, hl, fc1w, fc2w, xb, w1b, w2b);
  gemm1_kernel<<<384, 256, 0, stream>>>(xb, w1b, fc1b, y1, p1);
  gemm2_kernel<<<256, 256, 0, stream>>>(y1, w2b, fc2b, bn1g, bn1b, p1, y2, p2);
  fc3_kernel<<<256, 256, 0, stream>>>(y2, p2, bn2g, bn2b, fc3w, fc3b, out);
}